// Round 5
// baseline (16.681 us; speedup 1.0000x reference)
//
#include <hip/hip_runtime.h>

#define NBINS 64
#define FINE 512                     // 8 sub-bins per coarse bin
#define PIX_PER_CH (512 * 512)       // 262144
#define CH_TOTAL 24                  // 2 inputs x (4*3) channels
#define BLOCKS_PER_CH 32
#define PIX_PER_BLOCK (PIX_PER_CH / BLOCKS_PER_CH)   // 8192
#define THREADS 512                  // 8 waves
#define HBLOCKS (CH_TOTAL * BLOCKS_PER_CH)           // 768 = 3 per CU

#define O_LO (-36)                   // taps: d=(o+0.5)/8-0.5 in [-5,5); o in [-36,43]
#define NTAP 80
#define TAPS_PER_WAVE (NTAP / 8)     // 10

#define PAD(i) ((i) + ((i) >> 4))    // +1 pad per 16 words
#define PFINE (FINE + (FINE >> 4))   // 544

#define GPART_ROW (CH_TOTAL * NBINS) // 1536 floats per blk row
#define GPART_ROW4 (GPART_ROW / 4)   // 384 float4 per row

__device__ __forceinline__ float wexp(float d) {
    return __expf(-0.5f * d * d);
}

// Two kernel nodes, ZERO fill nodes, ZERO device-scope fences (R0/R2/R3
// post-mortems: a fill node costs ~+12 us in the graph; fence arrival
// machinery ~+4-6 us; the kernel boundary gives cross-XCD visibility free).
// ws layout: [0, 196608) g_part f32 [blk][ch][bin]  (every slot plain-stored)

__global__ __launch_bounds__(THREADS) void hist_kernel(
        const float* __restrict__ pred, const float* __restrict__ target,
        float* __restrict__ g_part) {
    __shared__ int fineI[PFINE];     // padded per-block fine histogram
    __shared__ float hpart[NBINS];   // cross-wave partial coarse bins
    __shared__ int sLo, sHi;

    const int tid = threadIdx.x;
    const int lane = tid & 63, wave = tid >> 6;
    const int b = blockIdx.x;
    const int gch = b / BLOCKS_PER_CH;        // 0..23
    const int blk = b - gch * BLOCKS_PER_CH;  // 0..31
    const float4* src4 = reinterpret_cast<const float4*>(
        (gch < 12 ? pred + gch * PIX_PER_CH
                  : target + (gch - 12) * PIX_PER_CH)
        + blk * PIX_PER_BLOCK);

    // issue all 4 independent float4 loads FIRST; LDS init hides under them
    float4 v[4];
    #pragma unroll
    for (int it = 0; it < 4; ++it)
        v[it] = src4[it * THREADS + tid];

    for (int i = tid; i < PFINE; i += THREADS) fineI[i] = 0;
    if (tid < NBINS) hpart[tid] = 0.f;
    if (tid == 0) { sLo = 0; sHi = 0; }
    __syncthreads();

    const float HI = 1.0f - 1e-6f;
    int cLo = 0, cHi = 0;

    #pragma unroll
    for (int it = 0; it < 4; ++it) {
        float xs[4] = {v[it].x, v[it].y, v[it].z, v[it].w};
        #pragma unroll
        for (int k = 0; k < 4; ++k) {
            float y = fmaf(xs[k], 0.5f, 0.5f);
            if (y <= 0.f) {
                ++cLo;               // clipped: analytic fold, no scatter
            } else if (y >= HI) {
                ++cHi;
            } else {
                int f = (int)(y * (float)FINE);      // [0, 511]
                atomicAdd(&fineI[PAD(f)], 1);
            }
        }
    }

    // wave-reduce clip counts, one LDS atomic per wave
    #pragma unroll
    for (int off = 32; off; off >>= 1) {
        cLo += __shfl_down(cLo, off, 64);
        cHi += __shfl_down(cHi, off, 64);
    }
    if (lane == 0) {
        if (cLo) atomicAdd(&sLo, cLo);
        if (cHi) atomicAdd(&sHi, cHi);
    }
    __syncthreads();

    // Fused conv, bin-per-lane: lane owns coarse bin `lane`; wave w covers
    // taps [w*10, w*10+10). Read stride ~8.5 words -> ~2 lanes/bank (free).
    float acc = 0.f;
    #pragma unroll
    for (int s = 0; s < TAPS_PER_WAVE; ++s) {
        int o = O_LO + wave * TAPS_PER_WAVE + s;
        float d = fmaf((float)o + 0.5f, 0.125f, -0.5f);
        float kv = wexp(d);
        int idx = (lane << 3) + o;
        if (idx >= 0 && idx < FINE)
            acc = fmaf((float)fineI[PAD(idx)], kv, acc);
    }
    // fold clipped-pixel mass into edge bins analytically, per block (linear,
    // so identical to deferred folding). Verified absmax 0.0 in R0/R2/R3.
    if (wave == 0) {
        if (lane <= 6)
            acc = fmaf((float)sLo, wexp(-0.5f - (float)lane), acc);
        if (lane >= 57) {
            float t = fmaf(HI, 64.f, -0.5f);
            acc = fmaf((float)sHi, wexp(t - (float)lane), acc);
        }
    }
    if (acc != 0.f) atomicAdd(&hpart[lane], acc);   // 8-way cross-wave combine
    __syncthreads();

    // coalesced 256 B row store: [blk][ch][bin]; every slot written -> no init
    if (tid < NBINS)
        g_part[blk * GPART_ROW + gch * NBINS + tid] = hpart[tid];
}

__global__ __launch_bounds__(1024) void finalize_kernel(
        const float* __restrict__ g_part, float* __restrict__ out) {
    __shared__ float h2[2][GPART_ROW];   // 2 x 1536 floats = 12 KB
    __shared__ float csum[96];
    __shared__ float inv[CH_TOTAL];
    __shared__ float wred[16];
    const int tid = threadIdx.x;

    // phase 1: two wave-aligned groups sum 16 rows each, FULL unroll ->
    // all 196 KB of reads in flight at once (latency-bound, not BW-bound).
    {
        int g = -1, col = 0;
        if (tid < 384)                      { g = 0; col = tid; }        // waves 0-5
        else if (tid >= 512 && tid < 896)   { g = 1; col = tid - 512; }  // waves 8-13
        if (g >= 0) {
            const float4* gp = reinterpret_cast<const float4*>(g_part)
                             + g * 16 * GPART_ROW4 + col;
            float4 s = make_float4(0.f, 0.f, 0.f, 0.f);
            #pragma unroll
            for (int r = 0; r < 16; ++r) {
                float4 w = gp[r * GPART_ROW4];
                s.x += w.x; s.y += w.y; s.z += w.z; s.w += w.w;
            }
            reinterpret_cast<float4*>(h2[g])[col] = s;
        }
    }
    __syncthreads();

    // combine the two row-halves; result lives in h2[0]
    if (tid < 384) {
        float4 a = reinterpret_cast<float4*>(h2[0])[tid];
        float4 b = reinterpret_cast<float4*>(h2[1])[tid];
        a.x += b.x; a.y += b.y; a.z += b.z; a.w += b.w;
        reinterpret_cast<float4*>(h2[0])[tid] = a;
    }
    __syncthreads();

    const float* h = h2[0];

    // per-channel sums: 4 partial lanes per channel, then combine
    if (tid < 96) {
        int c = tid >> 2, q = tid & 3;
        float s = 0.f;
        #pragma unroll
        for (int j = 0; j < 16; ++j) s += h[c * NBINS + q * 16 + j];
        csum[tid] = s;
    }
    __syncthreads();
    if (tid < CH_TOTAL)
        inv[tid] = 1.0f / (csum[4 * tid] + csum[4 * tid + 1]
                         + csum[4 * tid + 2] + csum[4 * tid + 3] + 1e-8f);
    __syncthreads();

    float a2 = 0.f;
    if (tid < 768) {                        // one element each
        int c = tid >> 6;
        float pa = h[tid] * inv[c];
        float pb = h[12 * NBINS + tid] * inv[12 + c];
        a2 = fabsf(pa - pb);
    }
    #pragma unroll
    for (int off = 32; off; off >>= 1) a2 += __shfl_down(a2, off, 64);
    if ((tid & 63) == 0) wred[tid >> 6] = a2;
    __syncthreads();
    if (tid == 0) {
        float total = 0.f;
        #pragma unroll
        for (int w2 = 0; w2 < 12; ++w2) total += wred[w2];
        out[0] = total * (1.0f / 768.0f);
    }
}

extern "C" void kernel_launch(void* const* d_in, const int* in_sizes, int n_in,
                              void* d_out, int out_size, void* d_ws, size_t ws_size,
                              hipStream_t stream) {
    const float* pred = (const float*)d_in[0];
    const float* target = (const float*)d_in[1];
    float* out = (float*)d_out;
    float* g_part = (float*)d_ws;                     // 49152 f32, all written

    hist_kernel<<<HBLOCKS, THREADS, 0, stream>>>(pred, target, g_part);
    finalize_kernel<<<1, 1024, 0, stream>>>(g_part, out);
}

// Round 7
// 16.446 us; speedup vs baseline: 1.0143x; 1.0143x over previous
//
#include <hip/hip_runtime.h>

#define NBINS 64
#define FINE 512                     // 8 sub-bins per coarse bin
#define PIX_PER_CH (512 * 512)       // 262144
#define CH_TOTAL 24                  // 2 inputs x (4*3) channels
#define BLOCKS_PER_CH 32
#define PIX_PER_BLOCK (PIX_PER_CH / BLOCKS_PER_CH)   // 8192
#define THREADS 512                  // 8 waves
#define HBLOCKS (CH_TOTAL * BLOCKS_PER_CH)           // 768 = 3 per CU, balanced

#define O_LO (-36)                   // taps: d=(o+0.5)/8-0.5 in [-5,5); o in [-36,43]
#define NTAP 80
#define TAPS_PER_WAVE (NTAP / 8)     // 10

#define PAD(i) ((i) + ((i) >> 4))    // +1 pad per 16 words
#define PFINE (FINE + (FINE >> 4))   // 544

#define GPART_ROW (CH_TOTAL * NBINS) // 1536 floats per blk row
#define GPART_ROW4 (GPART_ROW / 4)   // 384 float4 per row

typedef float f32x4 __attribute__((ext_vector_type(4)));  // builtin-compatible

__device__ __forceinline__ float wexp(float d) {
    return __expf(-0.5f * d * d);
}

// Two kernel nodes, ZERO fill nodes, ZERO device-scope fences.
// Session ledger: fill node in graph = +9..15 us (R0/R2); fence arrival
// machinery = +4..6 us (R0 vs R3); fork-join capture needs hipEvent* (banned).
// => the 2-node shape is structurally forced and cheapest.
// ws layout: [0, 196608) g_part f32 [blk][ch][bin]  (every slot plain-stored)

__global__ __launch_bounds__(THREADS) void hist_kernel(
        const float* __restrict__ pred, const float* __restrict__ target,
        float* __restrict__ g_part) {
    __shared__ int fineI[PFINE];     // padded per-block fine histogram
    __shared__ float hpart[NBINS];   // cross-wave partial coarse bins
    __shared__ int sLo, sHi;

    const int tid = threadIdx.x;
    const int lane = tid & 63, wave = tid >> 6;
    const int b = blockIdx.x;
    const int gch = b / BLOCKS_PER_CH;        // 0..23
    const int blk = b - gch * BLOCKS_PER_CH;  // 0..31
    const f32x4* src4 = reinterpret_cast<const f32x4*>(
        (gch < 12 ? pred + gch * PIX_PER_CH
                  : target + (gch - 12) * PIX_PER_CH)
        + blk * PIX_PER_BLOCK);

    // issue all 4 independent 16B loads FIRST (LDS init hides under them);
    // non-temporal: read-once stream, don't allocate/pollute L2
    f32x4 v[4];
    #pragma unroll
    for (int it = 0; it < 4; ++it)
        v[it] = __builtin_nontemporal_load(src4 + it * THREADS + tid);

    for (int i = tid; i < PFINE; i += THREADS) fineI[i] = 0;
    if (tid < NBINS) hpart[tid] = 0.f;
    if (tid == 0) { sLo = 0; sHi = 0; }
    __syncthreads();

    const float HI = 1.0f - 1e-6f;
    int cLo = 0, cHi = 0;

    #pragma unroll
    for (int it = 0; it < 4; ++it) {
        #pragma unroll
        for (int k = 0; k < 4; ++k) {
            float y = fmaf(v[it][k], 0.5f, 0.5f);
            if (y <= 0.f) {
                ++cLo;               // clipped: analytic fold, no scatter
            } else if (y >= HI) {
                ++cHi;
            } else {
                int f = (int)(y * (float)FINE);      // [0, 511]
                atomicAdd(&fineI[PAD(f)], 1);
            }
        }
    }

    // wave-reduce clip counts, one LDS atomic per wave
    #pragma unroll
    for (int off = 32; off; off >>= 1) {
        cLo += __shfl_down(cLo, off, 64);
        cHi += __shfl_down(cHi, off, 64);
    }
    if (lane == 0) {
        if (cLo) atomicAdd(&sLo, cLo);
        if (cHi) atomicAdd(&sHi, cHi);
    }
    __syncthreads();

    // Fused conv, bin-per-lane: lane owns coarse bin `lane`; wave w covers
    // taps [w*10, w*10+10). Read stride ~8.5 words -> ~2 lanes/bank (free).
    float acc = 0.f;
    #pragma unroll
    for (int s = 0; s < TAPS_PER_WAVE; ++s) {
        int o = O_LO + wave * TAPS_PER_WAVE + s;
        float d = fmaf((float)o + 0.5f, 0.125f, -0.5f);
        float kv = wexp(d);
        int idx = (lane << 3) + o;
        if (idx >= 0 && idx < FINE)
            acc = fmaf((float)fineI[PAD(idx)], kv, acc);
    }
    // fold clipped-pixel mass into edge bins analytically, per block (linear,
    // so identical to deferred folding). Verified absmax 0.0 R0/R2/R3/R4.
    if (wave == 0) {
        if (lane <= 6)
            acc = fmaf((float)sLo, wexp(-0.5f - (float)lane), acc);
        if (lane >= 57) {
            float t = fmaf(HI, 64.f, -0.5f);
            acc = fmaf((float)sHi, wexp(t - (float)lane), acc);
        }
    }
    if (acc != 0.f) atomicAdd(&hpart[lane], acc);   // 8-way cross-wave combine
    __syncthreads();

    // coalesced 256 B row store: [blk][ch][bin]; every slot written -> no init
    if (tid < NBINS)
        g_part[blk * GPART_ROW + gch * NBINS + tid] = hpart[tid];
}

// finalize: R3's exact measured-best form (512 thr, unroll-8). R4's 1024-thr
// full-unroll variant was +0.23 us (null-to-negative) -> reverted.
__global__ __launch_bounds__(512) void finalize_kernel(
        const float* __restrict__ g_part, float* __restrict__ out) {
    __shared__ float h[CH_TOTAL * NBINS];   // 1536
    __shared__ float csum[96];
    __shared__ float inv[CH_TOTAL];
    __shared__ float wred[8];
    const int tid = threadIdx.x;

    // sum the 32 per-block rows; fully coalesced (384 threads read consecutive
    // float4 within each 6 KB row), 32 independent loads per thread.
    if (tid < 384) {
        const float4* gp = reinterpret_cast<const float4*>(g_part) + tid;
        float4 s = make_float4(0.f, 0.f, 0.f, 0.f);
        #pragma unroll 8
        for (int r = 0; r < BLOCKS_PER_CH; ++r) {
            float4 w = gp[r * GPART_ROW4];
            s.x += w.x; s.y += w.y; s.z += w.z; s.w += w.w;
        }
        reinterpret_cast<float4*>(h)[tid] = s;
    }
    __syncthreads();

    // per-channel sums: 4 partial lanes per channel, then combine
    if (tid < 96) {
        int c = tid >> 2, q = tid & 3;
        float s = 0.f;
        #pragma unroll
        for (int j = 0; j < 16; ++j) s += h[c * NBINS + q * 16 + j];
        csum[tid] = s;
    }
    __syncthreads();
    if (tid < CH_TOTAL)
        inv[tid] = 1.0f / (csum[4 * tid] + csum[4 * tid + 1]
                         + csum[4 * tid + 2] + csum[4 * tid + 3] + 1e-8f);
    __syncthreads();

    float a2 = 0.f;
    for (int i = tid; i < 12 * NBINS; i += 512) {   // 768: 2 iters
        int c = i >> 6;
        float pa = h[i] * inv[c];
        float pb = h[12 * NBINS + i] * inv[12 + c];
        a2 += fabsf(pa - pb);
    }
    #pragma unroll
    for (int off = 32; off; off >>= 1) a2 += __shfl_down(a2, off, 64);
    if ((tid & 63) == 0) wred[tid >> 6] = a2;
    __syncthreads();
    if (tid == 0) {
        float total = 0.f;
        #pragma unroll
        for (int w2 = 0; w2 < 8; ++w2) total += wred[w2];
        out[0] = total * (1.0f / 768.0f);
    }
}

extern "C" void kernel_launch(void* const* d_in, const int* in_sizes, int n_in,
                              void* d_out, int out_size, void* d_ws, size_t ws_size,
                              hipStream_t stream) {
    const float* pred = (const float*)d_in[0];
    const float* target = (const float*)d_in[1];
    float* out = (float*)d_out;
    float* g_part = (float*)d_ws;                     // 49152 f32, all written

    hist_kernel<<<HBLOCKS, THREADS, 0, stream>>>(pred, target, g_part);
    finalize_kernel<<<1, 512, 0, stream>>>(g_part, out);
}